// Round 10
// baseline (35.525 us; speedup 1.0000x reference)
//
#include <hip/hip_runtime.h>
#include <hip/hip_bf16.h>

#define RES_    2048
#define CSTEPS  128     // steps per workgroup
#define NWG     512     // 65536 / CSTEPS
#define TILE_   48      // span <= 8px movement + 32 window = 40 <= 48 (3x3 MFMA tiles)
#define KPAD    136     // 128 + 8 halfs pad: row stride 272B, 16B-aligned
#define NTHR    576     // 9 waves: one 16x16 output tile each

typedef _Float16 half8 __attribute__((ext_vector_type(8)));
typedef float   float4_ __attribute__((ext_vector_type(4)));

__global__ __launch_bounds__(1024) void zero_out(float4_* __restrict__ out) {
    out[(size_t)blockIdx.x * 1024 + threadIdx.x] = float4_{0.f, 0.f, 0.f, 0.f};
}

__global__ __launch_bounds__(NTHR) void bezier_scatter(const float* __restrict__ cp,
                                                       float* __restrict__ out) {
    __shared__ _Float16 sExT[TILE_][KPAD];   // [col_offset][step], masked exp_x
    __shared__ _Float16 sEyT[TILE_][KPAD];   // [col_offset][step], masked exp_y
    __shared__ float s_cx[CSTEPS], s_cy[CSTEPS];
    __shared__ int   s_bx[CSTEPS], s_by[CSTEPS];
    __shared__ int   s_Ax, s_Ay;

    const int tid = threadIdx.x;
    const int chunk = (int)(__brev((unsigned)blockIdx.x) >> 23);

    // ---- Phase A: per-step curve position & block corner (exact ref float32 math) ----
    if (tid < CSTEPS) {
        const int gs = chunk * CSTEPS + tid;
        const float tl = (float)((double)gs / 65535.0);      // linspace(0,1,STEPS)
        const float to = (float)gs * (1.0f / 65536.0f);      // arange(STEPS)/STEPS (exact)
        const float p0x = cp[0], p0y = cp[1], p1x = cp[2], p1y = cp[3], p2x = cp[4], p2y = cp[5];
        const float ax = __fadd_rn(p0x, __fmul_rn(__fsub_rn(p1x, p0x), tl));
        const float ay = __fadd_rn(p0y, __fmul_rn(__fsub_rn(p1y, p0y), tl));
        const float bxf = __fadd_rn(p1x, __fmul_rn(__fsub_rn(p2x, p1x), tl));
        const float byf = __fadd_rn(p1y, __fmul_rn(__fsub_rn(p2y, p1y), tl));
        const float cx = __fadd_rn(ax, __fmul_rn(to, __fsub_rn(bxf, ax)));
        const float cy = __fadd_rn(ay, __fmul_rn(to, __fsub_rn(byf, ay)));
        const int bxi = min(max((int)floorf(__fmul_rn(2048.0f, cx)) - 16, 0), RES_ - 32);
        const int byi = min(max((int)floorf(__fmul_rn(2048.0f, cy)) - 16, 0), RES_ - 32);
        s_cx[tid] = cx; s_cy[tid] = cy; s_bx[tid] = bxi; s_by[tid] = byi;
        if (tid == 0) {
            s_Ax = min(max(bxi - 8, 0), RES_ - TILE_);
            s_Ay = min(max(byi - 8, 0), RES_ - TILE_);
        }
    }
    __syncthreads();
    const int Ax = s_Ax, Ay = s_Ay;

    // ---- Phase B: fill masked transposed f16 exp tables ----
    for (int it = tid; it < 2 * TILE_ * (CSTEPS / 8); it += NTHR) {
        const int half_ = TILE_ * (CSTEPS / 8);       // 768
        const int table = (it >= half_);
        const int rem   = it - table * half_;
        const int o     = rem >> 4;
        const int s0    = (rem & 15) * 8;
        const float* cc = table ? s_cy : s_cx;
        const int*   bb = table ? s_by : s_bx;
        const int  base = table ? Ay : Ax;
        const float ci  = (float)(base + o) * (1.0f / 2048.0f);
        half8 v;
        #pragma unroll
        for (int j = 0; j < 8; ++j) {
            const int s = s0 + j;
            const float d = __fsub_rn(cc[s], ci);
            const float e = __expf(-__fmul_rn(__fmul_rn(d, d), 5000.0f));
            const unsigned orel = (unsigned)(base + o - bb[s]);
            v[j] = (orel < 32u) ? (_Float16)e : (_Float16)0.0f;
        }
        *(half8*)(table ? &sEyT[o][s0] : &sExT[o][s0]) = v;
    }
    __syncthreads();

    // ---- Phase C: 48x48 tile = Ex^T (48x128) * Ey (128x48); 9 waves, 1 tile each ----
    const int lane = tid & 63;
    const int wid  = tid >> 6;
    const int mt   = wid / 3, nt = wid - mt * 3;
    const int arow = mt * 16 + (lane & 15);
    const int bcol = nt * 16 + (lane & 15);
    const int kgrp = (lane >> 4) * 8;
    float4_ acc = {0.f, 0.f, 0.f, 0.f};
    #pragma unroll
    for (int kb = 0; kb < CSTEPS / 32; ++kb) {
        const half8 aF = *(const half8*)&sExT[arow][kb * 32 + kgrp];
        const half8 bF = *(const half8*)&sEyT[bcol][kb * 32 + kgrp];
        acc = __builtin_amdgcn_mfma_f32_16x16x32_f16(aF, bF, acc, 0, 0, 0);
    }

    // ---- Flush ----
    const int coll = lane & 15;
    const int rowb = (lane >> 4) * 4;
    #pragma unroll
    for (int r = 0; r < 4; ++r) {
        const float v = acc[r];
        if (v != 0.0f) {
            const int gx = Ax + mt * 16 + rowb + r;
            const int gy = Ay + nt * 16 + coll;
            atomicAdd(&out[gx * RES_ + gy], v * (1.0f / 65536.0f));
        }
    }
}

extern "C" void kernel_launch(void* const* d_in, const int* in_sizes, int n_in,
                              void* d_out, int out_size, void* d_ws, size_t ws_size,
                              hipStream_t stream) {
    const float* cp = (const float*)d_in[0];
    float* out = (float*)d_out;
    // Intercept probe: R4 graph DOUBLED (zero,scatter,zero,scatter).
    // Output identical (2nd pass re-zeroes + re-adds same summands).
    // X - 21.2 = content + 2h  ->  separates fixed replay overhead g from kernel content.
    hipLaunchKernelGGL(zero_out, dim3(1024), dim3(1024), 0, stream, (float4_*)out);
    hipLaunchKernelGGL(bezier_scatter, dim3(NWG), dim3(NTHR), 0, stream, cp, out);
    hipLaunchKernelGGL(zero_out, dim3(1024), dim3(1024), 0, stream, (float4_*)out);
    hipLaunchKernelGGL(bezier_scatter, dim3(NWG), dim3(NTHR), 0, stream, cp, out);
}

// Round 11
// 27.512 us; speedup vs baseline: 1.2912x; 1.2912x over previous
//
#include <hip/hip_runtime.h>
#include <hip/hip_bf16.h>

#define RES_    2048
#define CSTEPS  64      // steps per workgroup (halved again: critical-path lever)
#define NWG     1024    // 65536 / CSTEPS
#define TILE_   48      // span <= 4px movement + 32 window = 36 <= 48 (3x3 MFMA tiles)
#define KPAD    72      // 64 + 8 halfs pad: row stride 144B, 16B-aligned
#define NTHR    576     // 9 waves: one 16x16 output tile each
#define GRP     (CSTEPS / 8)   // 8 step-groups per table column

typedef _Float16 half8 __attribute__((ext_vector_type(8)));
typedef float   float4_ __attribute__((ext_vector_type(4)));

__global__ __launch_bounds__(1024) void zero_out(float4_* __restrict__ out) {
    out[(size_t)blockIdx.x * 1024 + threadIdx.x] = float4_{0.f, 0.f, 0.f, 0.f};
}

__global__ __launch_bounds__(NTHR) void bezier_scatter(const float* __restrict__ cp,
                                                       float* __restrict__ out) {
    __shared__ _Float16 sExT[TILE_][KPAD];   // [col_offset][step], masked exp_x
    __shared__ _Float16 sEyT[TILE_][KPAD];   // [col_offset][step], masked exp_y
    __shared__ float s_cx[CSTEPS], s_cy[CSTEPS];
    __shared__ int   s_bx[CSTEPS], s_by[CSTEPS];
    __shared__ int   s_Ax, s_Ay;

    const int tid = threadIdx.x;

    // ---- Phase A: per-step curve position & block corner (exact ref float32 math) ----
    if (tid < CSTEPS) {
        const int gs = blockIdx.x * CSTEPS + tid;
        const float tl = (float)((double)gs / 65535.0);      // linspace(0,1,STEPS)
        const float to = (float)gs * (1.0f / 65536.0f);      // arange(STEPS)/STEPS (exact)
        const float p0x = cp[0], p0y = cp[1], p1x = cp[2], p1y = cp[3], p2x = cp[4], p2y = cp[5];
        const float ax = __fadd_rn(p0x, __fmul_rn(__fsub_rn(p1x, p0x), tl));
        const float ay = __fadd_rn(p0y, __fmul_rn(__fsub_rn(p1y, p0y), tl));
        const float bxf = __fadd_rn(p1x, __fmul_rn(__fsub_rn(p2x, p1x), tl));
        const float byf = __fadd_rn(p1y, __fmul_rn(__fsub_rn(p2y, p1y), tl));
        const float cx = __fadd_rn(ax, __fmul_rn(to, __fsub_rn(bxf, ax)));
        const float cy = __fadd_rn(ay, __fmul_rn(to, __fsub_rn(byf, ay)));
        const int bxi = min(max((int)floorf(__fmul_rn(2048.0f, cx)) - 16, 0), RES_ - 32);
        const int byi = min(max((int)floorf(__fmul_rn(2048.0f, cy)) - 16, 0), RES_ - 32);
        s_cx[tid] = cx; s_cy[tid] = cy; s_bx[tid] = bxi; s_by[tid] = byi;
        if (tid == 0) {
            // |bx_s - bx_0| <= 4 over 64 steps -> windows subset of [bx0-8, bx0+40) (48 wide)
            s_Ax = min(max(bxi - 8, 0), RES_ - TILE_);
            s_Ay = min(max(byi - 8, 0), RES_ - TILE_);
        }
    }
    __syncthreads();
    const int Ax = s_Ax, Ay = s_Ay;

    // ---- Phase B: fill masked transposed f16 exp tables ----
    // 2 tables * 48 cols * 8 step-groups(8) = 768 items over 576 threads
    for (int it = tid; it < 2 * TILE_ * GRP; it += NTHR) {
        const int half_ = TILE_ * GRP;                // 384
        const int table = (it >= half_);
        const int rem   = it - table * half_;
        const int o     = rem >> 3;                   // tile col offset 0..47
        const int s0    = (rem & (GRP - 1)) * 8;      // step group start
        const float* cc = table ? s_cy : s_cx;
        const int*   bb = table ? s_by : s_bx;
        const int  base = table ? Ay : Ax;
        const float ci  = (float)(base + o) * (1.0f / 2048.0f);   // exact (pow2 div)
        half8 v;
        #pragma unroll
        for (int j = 0; j < 8; ++j) {
            const int s = s0 + j;
            const float d = __fsub_rn(cc[s], ci);
            const float e = __expf(-__fmul_rn(__fmul_rn(d, d), 5000.0f));
            const unsigned orel = (unsigned)(base + o - bb[s]);
            v[j] = (orel < 32u) ? (_Float16)e : (_Float16)0.0f;
        }
        *(half8*)(table ? &sEyT[o][s0] : &sExT[o][s0]) = v;
    }
    __syncthreads();

    // ---- Phase C: 48x48 tile = Ex^T (48x64) * Ey (64x48); 9 waves, 1 tile each ----
    const int lane = tid & 63;
    const int wid  = tid >> 6;          // 0..8
    const int mt   = wid / 3, nt = wid - mt * 3;
    const int arow = mt * 16 + (lane & 15);
    const int bcol = nt * 16 + (lane & 15);
    const int kgrp = (lane >> 4) * 8;
    float4_ acc = {0.f, 0.f, 0.f, 0.f};
    #pragma unroll
    for (int kb = 0; kb < CSTEPS / 32; ++kb) {
        const half8 aF = *(const half8*)&sExT[arow][kb * 32 + kgrp];
        const half8 bF = *(const half8*)&sEyT[bcol][kb * 32 + kgrp];
        acc = __builtin_amdgcn_mfma_f32_16x16x32_f16(aF, bF, acc, 0, 0, 0);
    }

    // ---- Flush: C/D layout col = lane&15, row = (lane>>4)*4 + reg (confirmed R1) ----
    const int coll = lane & 15;
    const int rowb = (lane >> 4) * 4;
    #pragma unroll
    for (int r = 0; r < 4; ++r) {
        const float v = acc[r];
        if (v != 0.0f) {   // nonzero only inside valid clamped windows
            const int gx = Ax + mt * 16 + rowb + r;
            const int gy = Ay + nt * 16 + coll;
            atomicAdd(&out[gx * RES_ + gy], v * (1.0f / 65536.0f));  // /STEPS exact (pow2)
        }
    }
}

extern "C" void kernel_launch(void* const* d_in, const int* in_sizes, int n_in,
                              void* d_out, int out_size, void* d_ws, size_t ws_size,
                              hipStream_t stream) {
    const float* cp = (const float*)d_in[0];
    float* out = (float*)d_out;
    hipLaunchKernelGGL(zero_out, dim3(1024), dim3(1024), 0, stream, (float4_*)out);
    // 1024 WGs x 64 steps each (3 WGs/CU resident)
    hipLaunchKernelGGL(bezier_scatter, dim3(NWG), dim3(NTHR), 0, stream, cp, out);
}

// Round 12
// 21.041 us; speedup vs baseline: 1.6883x; 1.3075x over previous
//
#include <hip/hip_runtime.h>
#include <hip/hip_bf16.h>

#define RES_    2048
#define CSTEPS  128     // steps per workgroup (512 WGs = exactly 2/CU, single dispatch round)
#define NWG     512     // 65536 / CSTEPS
#define TILE_   48      // span <= 8px movement + 32 window = 40 <= 48 (3x3 MFMA tiles)
#define KPAD    136     // 128 + 8 halfs pad: row stride 272B, 16B-aligned
#define NTHR    576     // 9 waves: one 16x16 output tile each

typedef _Float16 half8 __attribute__((ext_vector_type(8)));
typedef float   float4_ __attribute__((ext_vector_type(4)));
typedef int     int4_   __attribute__((ext_vector_type(4)));

__global__ __launch_bounds__(1024) void zero_out(float4_* __restrict__ out) {
    out[(size_t)blockIdx.x * 1024 + threadIdx.x] = float4_{0.f, 0.f, 0.f, 0.f};
}

__global__ __launch_bounds__(NTHR) void bezier_scatter(const float* __restrict__ cp,
                                                       float* __restrict__ out) {
    __shared__ _Float16 sExT[TILE_][KPAD];   // [col_offset][step], masked exp_x
    __shared__ _Float16 sEyT[TILE_][KPAD];   // [col_offset][step], masked exp_y
    __shared__ float s_cx[CSTEPS], s_cy[CSTEPS];
    __shared__ int   s_bx[CSTEPS], s_by[CSTEPS];
    __shared__ int   s_Ax, s_Ay;

    const int tid = threadIdx.x;

    // ---- Phase A: per-step curve position & block corner (exact ref float32 math) ----
    if (tid < CSTEPS) {
        const int gs = blockIdx.x * CSTEPS + tid;
        const float tl = (float)((double)gs / 65535.0);      // linspace(0,1,STEPS)
        const float to = (float)gs * (1.0f / 65536.0f);      // arange(STEPS)/STEPS (exact)
        const float p0x = cp[0], p0y = cp[1], p1x = cp[2], p1y = cp[3], p2x = cp[4], p2y = cp[5];
        const float ax = __fadd_rn(p0x, __fmul_rn(__fsub_rn(p1x, p0x), tl));
        const float ay = __fadd_rn(p0y, __fmul_rn(__fsub_rn(p1y, p0y), tl));
        const float bxf = __fadd_rn(p1x, __fmul_rn(__fsub_rn(p2x, p1x), tl));
        const float byf = __fadd_rn(p1y, __fmul_rn(__fsub_rn(p2y, p1y), tl));
        const float cx = __fadd_rn(ax, __fmul_rn(to, __fsub_rn(bxf, ax)));
        const float cy = __fadd_rn(ay, __fmul_rn(to, __fsub_rn(byf, ay)));
        const int bxi = min(max((int)floorf(__fmul_rn(2048.0f, cx)) - 16, 0), RES_ - 32);
        const int byi = min(max((int)floorf(__fmul_rn(2048.0f, cy)) - 16, 0), RES_ - 32);
        s_cx[tid] = cx; s_cy[tid] = cy; s_bx[tid] = bxi; s_by[tid] = byi;
        if (tid == 0) {
            // |bx_s - bx_0| <= 8 over 128 steps -> windows subset of [bx0-8, bx0+40) (48 wide)
            s_Ax = min(max(bxi - 8, 0), RES_ - TILE_);
            s_Ay = min(max(byi - 8, 0), RES_ - TILE_);
        }
    }
    __syncthreads();
    const int Ax = s_Ax, Ay = s_Ay;

    // ---- Phase B: fill masked transposed f16 exp tables ----
    // 2 tables * 48 cols * 16 step-groups(8) = 1536 items over 576 threads.
    // Vectorized step loads: two b128 reads replace 8 stride-8 scalar reads
    // (kills the ~16-way bank conflict measured at ~712K cycles in R5/R8 CSVs).
    for (int it = tid; it < 2 * TILE_ * (CSTEPS / 8); it += NTHR) {
        const int half_ = TILE_ * (CSTEPS / 8);       // 768
        const int table = (it >= half_);
        const int rem   = it - table * half_;
        const int o     = rem >> 4;                   // tile col offset 0..47
        const int s0    = (rem & 15) * 8;             // step group start
        const float* cc = table ? s_cy : s_cx;
        const int*   bb = table ? s_by : s_bx;
        const int  base = table ? Ay : Ax;
        const float ci  = (float)(base + o) * (1.0f / 2048.0f);   // exact (pow2 div)
        const float4_ cA = *(const float4_*)&cc[s0];
        const float4_ cB = *(const float4_*)&cc[s0 + 4];
        const int4_   bA = *(const int4_*)&bb[s0];
        const int4_   bB = *(const int4_*)&bb[s0 + 4];
        half8 v;
        #pragma unroll
        for (int j = 0; j < 8; ++j) {
            const float cs = (j < 4) ? cA[j & 3] : cB[j & 3];   // static after unroll
            const int   bs = (j < 4) ? bA[j & 3] : bB[j & 3];
            const float d = __fsub_rn(cs, ci);
            const float e = __expf(-__fmul_rn(__fmul_rn(d, d), 5000.0f));
            const unsigned orel = (unsigned)(base + o - bs);
            v[j] = (orel < 32u) ? (_Float16)e : (_Float16)0.0f;
        }
        *(half8*)(table ? &sEyT[o][s0] : &sExT[o][s0]) = v;
    }
    __syncthreads();

    // ---- Phase C: 48x48 tile = Ex^T (48x128) * Ey (128x48); 9 waves, 1 tile each ----
    const int lane = tid & 63;
    const int wid  = tid >> 6;          // 0..8
    const int mt   = wid / 3, nt = wid - mt * 3;
    const int arow = mt * 16 + (lane & 15);
    const int bcol = nt * 16 + (lane & 15);
    const int kgrp = (lane >> 4) * 8;
    float4_ acc = {0.f, 0.f, 0.f, 0.f};
    #pragma unroll
    for (int kb = 0; kb < CSTEPS / 32; ++kb) {
        const half8 aF = *(const half8*)&sExT[arow][kb * 32 + kgrp];
        const half8 bF = *(const half8*)&sEyT[bcol][kb * 32 + kgrp];
        acc = __builtin_amdgcn_mfma_f32_16x16x32_f16(aF, bF, acc, 0, 0, 0);
    }

    // ---- Flush: C/D layout col = lane&15, row = (lane>>4)*4 + reg (confirmed R1) ----
    const int coll = lane & 15;
    const int rowb = (lane >> 4) * 4;
    #pragma unroll
    for (int r = 0; r < 4; ++r) {
        const float v = acc[r];
        if (v != 0.0f) {   // nonzero only inside valid clamped windows
            const int gx = Ax + mt * 16 + rowb + r;
            const int gy = Ay + nt * 16 + coll;
            atomicAdd(&out[gx * RES_ + gy], v * (1.0f / 65536.0f));  // /STEPS exact (pow2)
        }
    }
}

extern "C" void kernel_launch(void* const* d_in, const int* in_sizes, int n_in,
                              void* d_out, int out_size, void* d_ws, size_t ws_size,
                              hipStream_t stream) {
    const float* cp = (const float*)d_in[0];
    float* out = (float*)d_out;
    hipLaunchKernelGGL(zero_out, dim3(1024), dim3(1024), 0, stream, (float4_*)out);
    hipLaunchKernelGGL(bezier_scatter, dim3(NWG), dim3(NTHR), 0, stream, cp, out);
}